// Round 2
// baseline (242.316 us; speedup 1.0000x reference)
//
#include <hip/hip_runtime.h>

// RecurrentDecoder: B=8192, T=100, I=30, H=100.
// Fused LSTM: fp16 MFMA (16x16x32) for h@W_hh^T, W fragments register-resident,
// gate exchange via wave-private LDS round-trip (no DPP/swizzle).
// 256 blocks x 512 threads; block owns 32 batch rows.

#define LOG2E 1.44269504088896340736f

typedef _Float16 f16x8 __attribute__((ext_vector_type(8)));
typedef float    f32x4 __attribute__((ext_vector_type(4)));

__device__ __forceinline__ float sigm(float x) {
    return __builtin_amdgcn_rcpf(__builtin_amdgcn_exp2f(-LOG2E * x) + 1.0f);
}
__device__ __forceinline__ float tanh_f(float x) {
    return 1.0f - 2.0f * __builtin_amdgcn_rcpf(
        __builtin_amdgcn_exp2f(2.0f * LOG2E * x) + 1.0f);
}

// Gate-interleaved W layout: col = 4*u + s (u: unit 0..111 padded, s in {i,f,g,o}).
// K padded to 128. 28 n-tiles of 16 cols; tiles 25..27 are zero-pad units.
#define WSTR 136   // Wlds f16 row stride (272 B = 17*16 B)
#define HSTR 136   // hlds f16 row stride
#define GSTR 21    // gbuf f32 row stride (spreads banks)

__global__ __launch_bounds__(512, 2) void lstm_kernel(
    const float* __restrict__ x, const float* __restrict__ Wih,
    const float* __restrict__ Whh, const float* __restrict__ bih,
    const float* __restrict__ bhh, const float* __restrict__ Wd,
    const float* __restrict__ bd, float* __restrict__ out)
{
    // smem union: prologue = Wlds[448][WSTR] f16 (121856 B)
    //             loop     = gbuf[8][16][GSTR] f32 (10752 B) + part2[8][64] f32 (2048 B)
    __shared__ __align__(16) char smem[448 * WSTR * 2];
    __shared__ __align__(16) _Float16 hlds[32 * HSTR];   // 8704 B, NOT aliased

    _Float16* Wlds  = (_Float16*)smem;
    float*    gbuf  = (float*)smem;                       // [wave][16][GSTR]
    float*    part2 = (float*)(smem + 8 * 16 * GSTR * 4); // [8][64] at byte 10752

    const int tid  = threadIdx.x;
    const int wave = tid >> 6;
    const int l    = tid & 63;
    const int g    = l >> 4;      // 0..3
    const int c    = l & 15;      // col within 16-wide tile
    const int j    = c >> 2;      // unit within quad group
    const int s    = c & 3;       // gate slot
    const int m    = wave & 1;    // m-tile (16 batch rows)
    const int grp  = wave >> 1;   // 0..3 -> 7 n-tiles each
    const int b0   = blockIdx.x * 32;

    // ---- zero LDS (covers all K/col padding) ----
    for (int i = tid; i < 448 * WSTR / 2; i += 512) ((unsigned*)Wlds)[i] = 0u;
    for (int i = tid; i < 32 * HSTR / 2;  i += 512) ((unsigned*)hlds)[i] = 0u;
    __syncthreads();

    // ---- stage W_hh (row grow = s*100+u) -> fp16 Wlds col 4u+s ----
    for (int idx = tid; idx < 40000; idx += 512) {
        int grow = idx / 100;
        int k    = idx - grow * 100;
        int u    = grow % 100;
        int s2   = grow / 100;
        Wlds[(4 * u + s2) * WSTR + k] = (_Float16)Whh[idx];
    }
    __syncthreads();

    // ---- W fragments -> registers (B-operand: lane c = col, g = k-block) ----
    f16x8 wfrag[7][4];
    #pragma unroll
    for (int nt = 0; nt < 7; ++nt) {
        int gt = grp * 7 + nt;
        #pragma unroll
        for (int ks = 0; ks < 4; ++ks)
            wfrag[nt][ks] = *(const f16x8*)&Wlds[(gt * 16 + c) * WSTR + ks * 32 + g * 8];
    }

    // ---- per-lane xp in POST-transpose coords: this lane owns batch row `myrow`,
    //      units Uv[nt] = 4*(grp*7+nt)+j, all 4 gates. Also c-state, W_d. ----
    const int myrow = b0 + m * 16 + 4 * g + s;
    float xq[7][4], wd[7], creg[7];
    int   Uv[7];
    bool  val[7];
    #pragma unroll
    for (int nt = 0; nt < 7; ++nt) {
        int gt  = grp * 7 + nt;
        Uv[nt]  = 4 * gt + j;
        val[nt] = (Uv[nt] < 100);
        wd[nt]  = val[nt] ? Wd[Uv[nt]] : 0.0f;
        creg[nt] = 0.0f;
        #pragma unroll
        for (int r = 0; r < 4; ++r) xq[nt][r] = 0.0f;
    }
    for (int k = 0; k < 30; ++k) {
        float xv = x[myrow * 30 + k];
        #pragma unroll
        for (int nt = 0; nt < 7; ++nt) {
            if (val[nt]) {
                #pragma unroll
                for (int r = 0; r < 4; ++r)
                    xq[nt][r] += xv * Wih[(r * 100 + Uv[nt]) * 30 + k];
            }
        }
    }
    #pragma unroll
    for (int nt = 0; nt < 7; ++nt) {
        if (val[nt]) {
            #pragma unroll
            for (int r = 0; r < 4; ++r)
                xq[nt][r] += bih[r * 100 + Uv[nt]] + bhh[r * 100 + Uv[nt]];
        }
    }
    const float bdv = bd[0];
    __syncthreads();   // wfrag loads complete -> smem becomes gbuf/part2

    const int woff = wave * 16 * GSTR;

    // ---- recurrence ----
    for (int t = 0; t < 100; ++t) {
        // drain previous step's partials (reads part2(t-1); pre-mid-barrier)
        if (t > 0 && wave == 0 && l < 32) {
            int R = l, mm = R >> 4, g2 = (R >> 2) & 3, s2 = R & 3;
            float acc = bdv;
            #pragma unroll
            for (int gp = 0; gp < 4; ++gp)
                #pragma unroll
                for (int jj = 0; jj < 4; ++jj)
                    acc += part2[(gp * 2 + mm) * 64 + g2 * 16 + jj * 4 + s2];
            out[(b0 + R) * 100 + (t - 1)] = acc;
        }
        // A-fragments: h(t-1); lane c = batch row, g = k-block
        f16x8 af[4];
        #pragma unroll
        for (int ks = 0; ks < 4; ++ks)
            af[ks] = *(const f16x8*)&hlds[(m * 16 + c) * HSTR + ks * 32 + g * 8];
        __syncthreads();   // h(t-1)/part2(t-1) reads done; writes below are safe

        float po = 0.0f;
        #pragma unroll
        for (int nt = 0; nt < 7; ++nt) {
            f32x4 acc = {0.f, 0.f, 0.f, 0.f};
            #pragma unroll
            for (int ks = 0; ks < 4; ++ks)
                acc = __builtin_amdgcn_mfma_f32_16x16x32_f16(af[ks], wfrag[nt][ks], acc, 0, 0, 0);

            // Scatter C to wave-private gbuf: C[row=4g+r][col=c] (verified m89/m91 map)
            #pragma unroll
            for (int r = 0; r < 4; ++r)
                gbuf[woff + (4 * g + r) * GSTR + c] = acc[r];
            // wave-wide ds_write then ds_read: compiler inserts lgkmcnt wait;
            // no barrier needed (exchange is within this wave only).
            float w0 = gbuf[woff + (4 * g + s) * GSTR + 4 * j + 0] + xq[nt][0]; // i
            float w1 = gbuf[woff + (4 * g + s) * GSTR + 4 * j + 1] + xq[nt][1]; // f
            float w2 = gbuf[woff + (4 * g + s) * GSTR + 4 * j + 2] + xq[nt][2]; // g
            float w3 = gbuf[woff + (4 * g + s) * GSTR + 4 * j + 3] + xq[nt][3]; // o

            float ig = sigm(w0);
            float fg = sigm(w1);
            float gg = tanh_f(w2);
            float og = sigm(w3);
            float cg = fg * creg[nt] + ig * gg;
            creg[nt] = cg;
            float hv = og * tanh_f(cg);
            po += hv * wd[nt];
            // h(t): row = m*16+4g+s, k-col = unit index
            hlds[(m * 16 + 4 * g + s) * HSTR + (4 * (grp * 7 + nt) + j)] = (_Float16)hv;
        }
        part2[wave * 64 + l] = po;
        __syncthreads();   // h(t) + part2(t) visible to all
    }
    // final drain t=99
    if (wave == 0 && l < 32) {
        int R = l, mm = R >> 4, g2 = (R >> 2) & 3, s2 = R & 3;
        float acc = bdv;
        #pragma unroll
        for (int gp = 0; gp < 4; ++gp)
            #pragma unroll
            for (int jj = 0; jj < 4; ++jj)
                acc += part2[(gp * 2 + mm) * 64 + g2 * 16 + jj * 4 + s2];
        out[(b0 + R) * 100 + 99] = acc;
    }
}

extern "C" void kernel_launch(void* const* d_in, const int* in_sizes, int n_in,
                              void* d_out, int out_size, void* d_ws, size_t ws_size,
                              hipStream_t stream) {
    (void)in_sizes; (void)n_in; (void)out_size; (void)d_ws; (void)ws_size;
    const float* x   = (const float*)d_in[0];
    const float* Wih = (const float*)d_in[1];
    const float* Whh = (const float*)d_in[2];
    const float* bih = (const float*)d_in[3];
    const float* bhh = (const float*)d_in[4];
    const float* Wd  = (const float*)d_in[5];
    const float* bd  = (const float*)d_in[6];
    lstm_kernel<<<dim3(256), dim3(512), 0, stream>>>(
        x, Wih, Whh, bih, bhh, Wd, bd, (float*)d_out);
}

// Round 3
// 235.020 us; speedup vs baseline: 1.0310x; 1.0310x over previous
//
#include <hip/hip_runtime.h>

// RecurrentDecoder: B=8192, T=100, I=30, H=100.
// Fused LSTM, fp16 MFMA. 256 blocks x 768 threads (12 waves, 3/SIMD).
// W fragments register(AGPR)-resident; batched gbuf transpose round-trip:
// all MFMA scatters (b128, conflict-free) -> one wait -> gathers+activations.

#define LOG2E 1.44269504088896340736f

typedef _Float16 f16x8 __attribute__((ext_vector_type(8)));
typedef float    f32x4 __attribute__((ext_vector_type(4)));

__device__ __forceinline__ float sigm(float x) {
    return __builtin_amdgcn_rcpf(__builtin_amdgcn_exp2f(-LOG2E * x) + 1.0f);
}
__device__ __forceinline__ float tanh_f(float x) {
    return 1.0f - 2.0f * __builtin_amdgcn_rcpf(
        __builtin_amdgcn_exp2f(2.0f * LOG2E * x) + 1.0f);
}

// Gate-interleaved W layout: col = 4*u + s, units padded to 120 (30 n-tiles).
#define WSTR 136   // Wlds f16 row stride
#define HSTR 136   // hlds f16 row stride
#define GC1  20    // gbuf col stride (f32 words; mult of 4 -> b128-aligned writes)
#define GT0  320   // gbuf nt stride   = 16*GC1
#define GW   1600  // gbuf wave stride = 5*GT0

__global__ __launch_bounds__(768) void lstm_kernel(
    const float* __restrict__ x, const float* __restrict__ Wih,
    const float* __restrict__ Whh, const float* __restrict__ bih,
    const float* __restrict__ bhh, const float* __restrict__ Wd,
    const float* __restrict__ bd, float* __restrict__ out)
{
    // union: prologue Wlds[480][WSTR] f16 (130560 B)
    //        loop     gbuf 12*GW f32 (76800 B) + part 192 f32 (768 B)
    __shared__ __align__(16) char smem[480 * WSTR * 2];
    __shared__ __align__(16) _Float16 hlds[32 * HSTR];   // 8704 B

    _Float16* Wlds = (_Float16*)smem;
    float*    gbuf = (float*)smem;
    float*    part = (float*)(smem + 76800);

    const int tid  = threadIdx.x;
    const int wave = tid >> 6;      // 0..11
    const int l    = tid & 63;
    const int g    = l >> 4;        // 0..3
    const int c    = l & 15;
    const int j    = c >> 2;        // unit-in-quad
    const int s    = c & 3;         // gate slot
    const int m    = wave & 1;      // m-tile
    const int grp  = wave >> 1;     // 0..5 -> 5 n-tiles each
    const int b0   = blockIdx.x * 32;

    // ---- zero LDS (covers all padding) ----
    for (int i = tid; i < 480 * WSTR / 2; i += 768) ((unsigned*)Wlds)[i] = 0u;
    for (int i = tid; i < 32 * HSTR / 2;  i += 768) ((unsigned*)hlds)[i] = 0u;
    __syncthreads();

    // ---- stage W_hh (grow = s2*100+u) -> fp16 Wlds col 4u+s2 ----
    for (int idx = tid; idx < 40000; idx += 768) {
        int grow = idx / 100;
        int k    = idx - grow * 100;
        int u    = grow % 100;
        int s2   = grow / 100;
        Wlds[(4 * u + s2) * WSTR + k] = (_Float16)Whh[idx];
    }
    __syncthreads();

    // ---- W fragments -> registers (B-operand) ----
    f16x8 wfrag[5][4];
    #pragma unroll
    for (int nt = 0; nt < 5; ++nt) {
        int gt = grp * 5 + nt;
        #pragma unroll
        for (int ks = 0; ks < 4; ++ks)
            wfrag[nt][ks] = *(const f16x8*)&Wlds[(gt * 16 + c) * WSTR + ks * 32 + g * 8];
    }

    // ---- xp in post-transpose coords: lane owns row myrow, units 4*(grp*5+nt)+j ----
    const int myrow = b0 + m * 16 + 4 * g + s;
    float xq[5][4], wd[5], creg[5];
    int Uv[5]; bool val[5];
    #pragma unroll
    for (int nt = 0; nt < 5; ++nt) {
        int U   = 4 * (grp * 5 + nt) + j;
        Uv[nt]  = U;
        val[nt] = (U < 100);
        wd[nt]  = val[nt] ? Wd[U] : 0.0f;
        creg[nt] = 0.0f;
        #pragma unroll
        for (int r = 0; r < 4; ++r) xq[nt][r] = 0.0f;
    }
    for (int k = 0; k < 30; ++k) {
        float xv = x[myrow * 30 + k];
        #pragma unroll
        for (int nt = 0; nt < 5; ++nt) {
            if (val[nt]) {
                #pragma unroll
                for (int r = 0; r < 4; ++r)
                    xq[nt][r] += xv * Wih[(r * 100 + Uv[nt]) * 30 + k];
            }
        }
    }
    #pragma unroll
    for (int nt = 0; nt < 5; ++nt) {
        if (val[nt]) {
            #pragma unroll
            for (int r = 0; r < 4; ++r)
                xq[nt][r] += bih[r * 100 + Uv[nt]] + bhh[r * 100 + Uv[nt]];
        }
    }
    const float bdv = bd[0];
    __syncthreads();   // wfrag reads drained -> smem becomes gbuf/part

    // loop-invariant addresses
    const int wbase = wave * GW + c * GC1 + 4 * g;          // b128 write base (words)
    const int rbase = wave * GW + 80 * j + 4 * g + s;       // read base; +20r +320nt
    const int hbase = (m * 16 + 4 * g + s) * HSTR + 4 * grp * 5 + j; // + 4nt
    const int afb   = (m * 16 + c) * HSTR + g * 8;          // + 32ks

    // ---- recurrence ----
    for (int t = 0; t < 100; ++t) {
        // drain previous step's partials (before mid-barrier)
        if (t > 0 && wave == 0 && l < 32) {
            float a2 = bdv;
            #pragma unroll
            for (int gp = 0; gp < 6; ++gp) a2 += part[gp * 32 + l];
            out[(b0 + l) * 100 + (t - 1)] = a2;
        }
        // A-fragments: h(t-1)
        f16x8 af[4];
        #pragma unroll
        for (int ks = 0; ks < 4; ++ks)
            af[ks] = *(const f16x8*)&hlds[afb + ks * 32];
        __syncthreads();   // all h(t-1)/part reads done; writes below safe

        // phase 1: all MFMAs, scatter C tiles to wave-private gbuf (b128)
        #pragma unroll
        for (int nt = 0; nt < 5; ++nt) {
            f32x4 acc = {0.f, 0.f, 0.f, 0.f};
            #pragma unroll
            for (int ks = 0; ks < 4; ++ks)
                acc = __builtin_amdgcn_mfma_f32_16x16x32_f16(af[ks], wfrag[nt][ks], acc, 0, 0, 0);
            *(f32x4*)&gbuf[wbase + nt * GT0] = acc;   // [nt][col=c][row]
        }

        // phase 2: gather transposed gates (one lgkmcnt wait), activations
        float po = 0.0f;
        #pragma unroll
        for (int nt = 0; nt < 5; ++nt) {
            float w0 = gbuf[rbase + 0 * GC1 + nt * GT0] + xq[nt][0]; // i
            float w1 = gbuf[rbase + 1 * GC1 + nt * GT0] + xq[nt][1]; // f
            float w2 = gbuf[rbase + 2 * GC1 + nt * GT0] + xq[nt][2]; // g
            float w3 = gbuf[rbase + 3 * GC1 + nt * GT0] + xq[nt][3]; // o

            float ig = sigm(w0);
            float fg = sigm(w1);
            float gg = tanh_f(w2);
            float og = sigm(w3);
            float cg = fg * creg[nt] + ig * gg;
            creg[nt] = cg;
            float hv = og * tanh_f(cg);
            po += hv * wd[nt];
            hlds[hbase + 4 * nt] = (_Float16)hv;      // h(t): row, unit col
        }
        // reduce po over j (lane bits 2,3): xor4, xor8
        po += __int_as_float(__builtin_amdgcn_ds_swizzle(__float_as_int(po), 0x101F));
        po += __int_as_float(__builtin_amdgcn_ds_swizzle(__float_as_int(po), 0x201F));
        if ((l & 12) == 0)
            part[grp * 32 + m * 16 + 4 * g + s] = po;
        __syncthreads();   // h(t) + part(t) visible
    }
    // final drain t=99
    if (wave == 0 && l < 32) {
        float a2 = bdv;
        #pragma unroll
        for (int gp = 0; gp < 6; ++gp) a2 += part[gp * 32 + l];
        out[(b0 + l) * 100 + 99] = a2;
    }
}

extern "C" void kernel_launch(void* const* d_in, const int* in_sizes, int n_in,
                              void* d_out, int out_size, void* d_ws, size_t ws_size,
                              hipStream_t stream) {
    (void)in_sizes; (void)n_in; (void)out_size; (void)d_ws; (void)ws_size;
    const float* x   = (const float*)d_in[0];
    const float* Wih = (const float*)d_in[1];
    const float* Whh = (const float*)d_in[2];
    const float* bih = (const float*)d_in[3];
    const float* bhh = (const float*)d_in[4];
    const float* Wd  = (const float*)d_in[5];
    const float* bd  = (const float*)d_in[6];
    lstm_kernel<<<dim3(256), dim3(768), 0, stream>>>(
        x, Wih, Whh, bih, bhh, Wd, bd, (float*)d_out);
}

// Round 4
// 198.941 us; speedup vs baseline: 1.2180x; 1.1814x over previous
//
#include <hip/hip_runtime.h>

// RecurrentDecoder: B=8192, T=100, I=30, H=100.
// Transpose-free fused LSTM: per-gate column blocks -> 4 MFMA acc sets per
// unit-tile, so each lane owns i,f,g,o of its (row,unit) pairs in registers.
// 256 blocks x 512 threads (8 waves). W frags + xp + c-state register-resident.
// Double-buffered h in LDS -> single barrier per step.

#define LOG2E 1.44269504088896340736f

typedef _Float16 f16x8 __attribute__((ext_vector_type(8)));
typedef float    f32x4 __attribute__((ext_vector_type(4)));

__device__ __forceinline__ float sigm(float x) {
    return __builtin_amdgcn_rcpf(__builtin_amdgcn_exp2f(-LOG2E * x) + 1.0f);
}
__device__ __forceinline__ float tanh_f(float x) {
    return 1.0f - 2.0f * __builtin_amdgcn_rcpf(
        __builtin_amdgcn_exp2f(2.0f * LOG2E * x) + 1.0f);
}

#define WSTR 136            // Wlds f16 k-stride
#define HSTR 136            // hlds f16 k-stride (b128-aligned, 2-way max)
#define PSTR 69             // part f32 row stride (odd*? 69: row*69 mod 32 bijective-ish)
#define PBUF (32 * PSTR)    // one part buffer, words
#define OUTB_OFF (2 * PBUF) // outb after 2 part buffers, words

__global__ __launch_bounds__(512, 2) void lstm_kernel(
    const float* __restrict__ x, const float* __restrict__ Wih,
    const float* __restrict__ Whh, const float* __restrict__ bih,
    const float* __restrict__ bhh, const float* __restrict__ Wd,
    const float* __restrict__ bd, float* __restrict__ out)
{
    // union: prologue Wlds[512 cols][WSTR] f16 = 139264 B
    //        loop     part[2][32][PSTR] f32 (17664 B) + outb[2][32][100] f32 (25600 B)
    __shared__ __align__(16) char smem[512 * WSTR * 2];
    __shared__ __align__(16) _Float16 hlds[2][32 * HSTR];   // 17408 B (dbuf)

    _Float16* Wlds = (_Float16*)smem;
    float*    part = (float*)smem;
    float*    outb = (float*)smem + OUTB_OFF;

    const int tid  = threadIdx.x;
    const int wave = tid >> 6;     // 0..7
    const int l    = tid & 63;
    const int g    = l >> 4;       // 0..3
    const int c    = l & 15;
    const int m    = wave & 1;     // 16-row half
    const int grp  = wave >> 1;    // 0..3 -> units grp*32 .. grp*32+31
    const int b0   = blockIdx.x * 32;

    // ---- zero LDS (covers all padding; hlds buf0 = h(-1) = 0) ----
    for (int i = tid; i < 512 * WSTR / 2; i += 512) ((unsigned*)Wlds)[i] = 0u;
    for (int i = tid; i < 2 * 32 * HSTR / 2; i += 512) ((unsigned*)&hlds[0][0])[i] = 0u;
    __syncthreads();

    // ---- stage W_hh: global row s2*100+u -> Wlds col s2*128+u (per-gate blocks) ----
    for (int idx = tid; idx < 40000; idx += 512) {
        int grow = idx / 100;
        int k    = idx - grow * 100;
        int u    = grow % 100;
        int s2   = grow / 100;
        Wlds[(s2 * 128 + u) * WSTR + k] = (_Float16)Whh[idx];
    }
    __syncthreads();

    // ---- W fragments -> registers: set (nt, s), B[col=unit][k] ----
    f16x8 wfrag[2][4][4];
    #pragma unroll
    for (int nt = 0; nt < 2; ++nt) {
        const int u0 = grp * 32 + nt * 16 + c;
        #pragma unroll
        for (int s = 0; s < 4; ++s)
            #pragma unroll
            for (int ks = 0; ks < 4; ++ks)
                wfrag[nt][s][ks] =
                    *(const f16x8*)&Wlds[(s * 128 + u0) * WSTR + ks * 32 + g * 8];
    }

    // ---- xq = xp in C-fragment coords (MFMA acc init); c-state; W_d ----
    const int row0 = b0 + m * 16 + 4 * g;   // lane's rows: row0+r
    const int uu0  = grp * 32 + c;          // lane's unit (nt=0); +16 for nt=1
    f32x4 xq[2][4];
    float creg[2][4];
    float wd[2];
    #pragma unroll
    for (int nt = 0; nt < 2; ++nt) {
        int u = uu0 + nt * 16;
        wd[nt] = (u < 100) ? Wd[u] : 0.0f;
        #pragma unroll
        for (int s = 0; s < 4; ++s) xq[nt][s] = (f32x4){0.f, 0.f, 0.f, 0.f};
        #pragma unroll
        for (int r = 0; r < 4; ++r) creg[nt][r] = 0.0f;
    }
    for (int k = 0; k < 30; ++k) {
        float xv[4];
        #pragma unroll
        for (int r = 0; r < 4; ++r) xv[r] = x[(row0 + r) * 30 + k];
        #pragma unroll
        for (int nt = 0; nt < 2; ++nt) {
            int u = uu0 + nt * 16;
            if (u < 100) {
                #pragma unroll
                for (int s = 0; s < 4; ++s) {
                    float w = Wih[(s * 100 + u) * 30 + k];
                    #pragma unroll
                    for (int r = 0; r < 4; ++r) xq[nt][s][r] += xv[r] * w;
                }
            }
        }
    }
    #pragma unroll
    for (int nt = 0; nt < 2; ++nt) {
        int u = uu0 + nt * 16;
        if (u < 100) {
            #pragma unroll
            for (int s = 0; s < 4; ++s) {
                float b = bih[s * 100 + u] + bhh[s * 100 + u];
                #pragma unroll
                for (int r = 0; r < 4; ++r) xq[nt][s][r] += b;
            }
        }
    }
    const float bdv = bd[0];
    __syncthreads();   // Wlds reads drained -> smem becomes part/outb

    const int afb = (m * 16 + c) * HSTR + g * 8;            // + ks*32
    const int hwb = (m * 16 + 4 * g) * HSTR + grp * 32 + c; // + r*HSTR + nt*16
    const int pwb = (m * 16 + 4 * g) * PSTR + grp * 16 + c; // + r*PSTR

    // ---- recurrence: ONE barrier per step ----
    for (int t = 0; t < 100; ++t) {
        const _Float16* hr = hlds[t & 1];
        _Float16*       hw = hlds[(t & 1) ^ 1];

        f16x8 af[4];
        #pragma unroll
        for (int ks = 0; ks < 4; ++ks)
            af[ks] = *(const f16x8*)&hr[afb + ks * 32];

        // drain part(t-1) -> outb (waves 0,1; reads the OTHER part buffer)
        if (t > 0 && wave < 2 && l < 32) {
            const float* ps = part + ((t - 1) & 1) * PBUF + l * PSTR + wave * 32;
            float a2 = 0.0f;
            #pragma unroll
            for (int vv = 0; vv < 32; ++vv) a2 += ps[vv];
            outb[wave * 3200 + l * 100 + (t - 1)] = a2;
        }

        float po[4] = {0.f, 0.f, 0.f, 0.f};
        #pragma unroll
        for (int nt = 0; nt < 2; ++nt) {
            f32x4 acc[4];
            #pragma unroll
            for (int s = 0; s < 4; ++s) {
                f32x4 a = xq[nt][s];
                #pragma unroll
                for (int ks = 0; ks < 4; ++ks)
                    a = __builtin_amdgcn_mfma_f32_16x16x32_f16(
                            af[ks], wfrag[nt][s][ks], a, 0, 0, 0);
                acc[s] = a;
            }
            #pragma unroll
            for (int r = 0; r < 4; ++r) {
                float ig = sigm(acc[0][r]);
                float fg = sigm(acc[1][r]);
                float gg = tanh_f(acc[2][r]);
                float og = sigm(acc[3][r]);
                float cg = fg * creg[nt][r] + ig * gg;
                creg[nt][r] = cg;
                float hv = og * tanh_f(cg);
                po[r] += hv * wd[nt];
                hw[hwb + r * HSTR + nt * 16] = (_Float16)hv;   // h(t)
            }
        }
        float* pw = part + (t & 1) * PBUF;
        #pragma unroll
        for (int r = 0; r < 4; ++r)
            pw[pwb + r * PSTR] = po[r];
        __syncthreads();   // h(t) + part(t) visible; outb(t-1) done
    }

    // epilogue: drain t=99 (part buffer 1), then coalesced global write
    if (wave < 2 && l < 32) {
        const float* ps = part + PBUF + l * PSTR + wave * 32;
        float a2 = 0.0f;
        #pragma unroll
        for (int vv = 0; vv < 32; ++vv) a2 += ps[vv];
        outb[wave * 3200 + l * 100 + 99] = a2;
    }
    __syncthreads();
    for (int i = tid; i < 3200; i += 512)
        out[b0 * 100 + i] = outb[i] + outb[3200 + i] + bdv;
}

extern "C" void kernel_launch(void* const* d_in, const int* in_sizes, int n_in,
                              void* d_out, int out_size, void* d_ws, size_t ws_size,
                              hipStream_t stream) {
    (void)in_sizes; (void)n_in; (void)out_size; (void)d_ws; (void)ws_size;
    const float* x   = (const float*)d_in[0];
    const float* Wih = (const float*)d_in[1];
    const float* Whh = (const float*)d_in[2];
    const float* bih = (const float*)d_in[3];
    const float* bhh = (const float*)d_in[4];
    const float* Wd  = (const float*)d_in[5];
    const float* bd  = (const float*)d_in[6];
    lstm_kernel<<<dim3(256), dim3(512), 0, stream>>>(
        x, Wih, Whh, bih, bhh, Wd, bd, (float*)d_out);
}

// Round 6
// 193.475 us; speedup vs baseline: 1.2524x; 1.0282x over previous
//
#include <hip/hip_runtime.h>

// RecurrentDecoder: B=8192, T=100, I=30, H=100.
// Transpose-free fused LSTM, fp16 MFMA, per-gate column blocks.
// 256 blocks x 512 threads (8 waves). W frags (AGPR) + xp + c-state in regs.
// Pre-scaled weights (fold log2e), DPP row_ror po-reduction, balanced 4-lane
// drain with direct global stores, packed h write (cvt_pkrtz via u32 bitcast),
// all-MFMA-then-all-act scheduling. One barrier per step.

#define LOG2E 1.44269504088896340736f

typedef _Float16 f16x8 __attribute__((ext_vector_type(8)));
typedef float    f32x4 __attribute__((ext_vector_type(4)));

__device__ __forceinline__ float rcp_(float x) { return __builtin_amdgcn_rcpf(x); }
__device__ __forceinline__ float exp2_(float x) { return __builtin_amdgcn_exp2f(x); }

__device__ __forceinline__ unsigned pk_f16(float a, float b) {
    return __builtin_bit_cast(unsigned, __builtin_amdgcn_cvt_pkrtz(a, b));
}

template<int CTRL>
__device__ __forceinline__ float dpp_add(float x) {
    float t = __int_as_float(__builtin_amdgcn_update_dpp(
        0, __float_as_int(x), CTRL, 0xF, 0xF, true));
    return x + t;
}

#define WSTR 136            // Wlds f16 k-stride
#define HSTR 136            // hlds f16 k-stride

__global__ __launch_bounds__(512, 2) void lstm_kernel(
    const float* __restrict__ x, const float* __restrict__ Wih,
    const float* __restrict__ Whh, const float* __restrict__ bih,
    const float* __restrict__ bhh, const float* __restrict__ Wd,
    const float* __restrict__ bd, float* __restrict__ out)
{
    // union: prologue Wlds[512][WSTR] f16 = 139264 B; loop part2[2][32][4] f32 = 1 KB
    __shared__ __align__(16) char smem[512 * WSTR * 2];
    __shared__ __align__(16) _Float16 hlds[2][32 * HSTR];   // 17408 B (dbuf)

    _Float16* Wlds  = (_Float16*)smem;
    float*    part2 = (float*)smem;   // [2][32 rows][4 grp]

    const int tid  = threadIdx.x;
    const int wave = tid >> 6;     // 0..7
    const int l    = tid & 63;
    const int g    = l >> 4;       // 0..3
    const int c    = l & 15;
    const int m    = wave & 1;     // 16-row half
    const int grp  = wave >> 1;    // 0..3
    const int b0   = blockIdx.x * 32;

    // ---- zero LDS (padding + h(-1)=0; dead h-channels stay 0 forever) ----
    for (int i = tid; i < 512 * WSTR / 2; i += 512) ((unsigned*)Wlds)[i] = 0u;
    for (int i = tid; i < 2 * 32 * HSTR / 2; i += 512) ((unsigned*)&hlds[0][0])[i] = 0u;
    __syncthreads();

    // ---- stage W_hh, pre-scaled: i,f,o cols * -log2e; g cols * -2log2e.
    //      N-permutation: unit u -> col s*128 + 32*(u>>5) + 16*(u&1) + ((u&31)>>1)
    //      (tile 2G holds even units 32G+2c, tile 2G+1 odd units 32G+2c+1). ----
    for (int idx = tid; idx < 40000; idx += 512) {
        int grow = idx / 100;            // 0..399
        int k    = idx - grow * 100;     // h-channel (K dim, identity)
        int u    = grow % 100;
        int s2   = grow / 100;
        int col  = s2 * 128 + 32 * (u >> 5) + 16 * (u & 1) + ((u & 31) >> 1);
        float sc = (s2 == 2) ? (-2.0f * LOG2E) : (-LOG2E);
        Wlds[col * WSTR + k] = (_Float16)(Whh[idx] * sc);
    }
    __syncthreads();

    // ---- W fragments -> registers ----
    f16x8 wfrag[2][4][4];
    #pragma unroll
    for (int nt = 0; nt < 2; ++nt)
        #pragma unroll
        for (int s = 0; s < 4; ++s)
            #pragma unroll
            for (int ks = 0; ks < 4; ++ks)
                wfrag[nt][s][ks] = *(const f16x8*)
                    &Wlds[(s * 128 + grp * 32 + nt * 16 + c) * WSTR + ks * 32 + g * 8];

    // ---- xq (pre-scaled xp in C-frag coords), c-state, W_d ----
    // lane's units: uA = 32*grp + 2*c (nt0), uB = uA+1 (nt1) -- adjacent channels.
    const int row0 = b0 + m * 16 + 4 * g;
    const int uA   = 32 * grp + 2 * c;
    f32x4 xq[2][4];
    float creg[2][4];
    float wd[2];
    #pragma unroll
    for (int nt = 0; nt < 2; ++nt) {
        int u = uA + nt;
        wd[nt] = (u < 100) ? Wd[u] : 0.0f;
        #pragma unroll
        for (int s = 0; s < 4; ++s) xq[nt][s] = (f32x4){0.f, 0.f, 0.f, 0.f};
        #pragma unroll
        for (int r = 0; r < 4; ++r) creg[nt][r] = 0.0f;
    }
    for (int k = 0; k < 30; ++k) {
        float xv[4];
        #pragma unroll
        for (int r = 0; r < 4; ++r) xv[r] = x[(row0 + r) * 30 + k];
        #pragma unroll
        for (int nt = 0; nt < 2; ++nt) {
            int u = uA + nt;
            if (u < 100) {
                #pragma unroll
                for (int s = 0; s < 4; ++s) {
                    float w = Wih[(s * 100 + u) * 30 + k];
                    #pragma unroll
                    for (int r = 0; r < 4; ++r) xq[nt][s][r] += xv[r] * w;
                }
            }
        }
    }
    #pragma unroll
    for (int nt = 0; nt < 2; ++nt) {
        int u = uA + nt;
        if (u < 100) {
            #pragma unroll
            for (int s = 0; s < 4; ++s) {
                float sc = (s == 2) ? (-2.0f * LOG2E) : (-LOG2E);
                float b  = bih[s * 100 + u] + bhh[s * 100 + u];
                #pragma unroll
                for (int r = 0; r < 4; ++r)
                    xq[nt][s][r] = (xq[nt][s][r] + b) * sc;
            }
        }
    }
    const float bdv = bd[0];
    __syncthreads();   // Wlds reads drained -> smem becomes part2

    const int afb = (m * 16 + c) * HSTR + g * 8;             // + ks*32
    const int hwc = 32 * grp + 2 * c;                        // packed h channel
    float* const outp = out + (b0 + 4 * wave + l) * 100;     // drain rows (l<4)

    // ---- recurrence: ONE barrier per step ----
    for (int t = 0; t < 100; ++t) {
        const _Float16* hr = hlds[t & 1];
        _Float16*       hw = hlds[(t & 1) ^ 1];

        f16x8 af[4];
        #pragma unroll
        for (int ks = 0; ks < 4; ++ks)
            af[ks] = *(const f16x8*)&hr[afb + ks * 32];

        // drain step t-1: each wave handles rows 4w..4w+3 (lanes 0..3)
        if (t > 0 && l < 4) {
            const f32x4 v = *(const f32x4*)&part2[((t - 1) & 1) * 128 + (4 * wave + l) * 4];
            outp[t - 1] = v[0] + v[1] + v[2] + v[3] + bdv;
        }

        // phase 1: all 32 MFMAs (8 independent acc sets)
        f32x4 acc[2][4];
        #pragma unroll
        for (int nt = 0; nt < 2; ++nt)
            #pragma unroll
            for (int s = 0; s < 4; ++s) {
                f32x4 a = xq[nt][s];
                #pragma unroll
                for (int ks = 0; ks < 4; ++ks)
                    a = __builtin_amdgcn_mfma_f32_16x16x32_f16(
                            af[ks], wfrag[nt][s][ks], a, 0, 0, 0);
                acc[nt][s] = a;
            }

        // phase 2: activations (pre-acts already scaled by -log2e / -2log2e)
        float po[4];
        #pragma unroll
        for (int r = 0; r < 4; ++r) {
            float hv[2];
            #pragma unroll
            for (int nt = 0; nt < 2; ++nt) {
                float ig = rcp_(exp2_(acc[nt][0][r]) + 1.0f);
                float fg = rcp_(exp2_(acc[nt][1][r]) + 1.0f);
                float gg = fmaf(2.0f, rcp_(exp2_(acc[nt][2][r]) + 1.0f), -1.0f);
                float og = rcp_(exp2_(acc[nt][3][r]) + 1.0f);
                float cg = fmaf(fg, creg[nt][r], ig * gg);
                creg[nt][r] = cg;
                float th = fmaf(2.0f, rcp_(exp2_(cg * (-2.0f * LOG2E)) + 1.0f), -1.0f);
                hv[nt] = og * th;
            }
            po[r] = fmaf(hv[0], wd[0], hv[1] * wd[1]);
            *(unsigned*)&hw[(m * 16 + 4 * g + r) * HSTR + hwc] = pk_f16(hv[0], hv[1]);
        }

        // reduce po over the 16 c-lanes (DPP row_ror butterfly, pure VALU)
        #pragma unroll
        for (int r = 0; r < 4; ++r) {
            po[r] = dpp_add<0x128>(po[r]);   // ror 8
            po[r] = dpp_add<0x124>(po[r]);   // ror 4
            po[r] = dpp_add<0x122>(po[r]);   // ror 2
            po[r] = dpp_add<0x121>(po[r]);   // ror 1
        }
        if (c == 0) {
            #pragma unroll
            for (int r = 0; r < 4; ++r)
                part2[(t & 1) * 128 + (m * 16 + 4 * g + r) * 4 + grp] = po[r];
        }
        __syncthreads();   // h(t) + part2(t) visible
    }

    // final drain t=99 (buffer 1)
    if (l < 4) {
        const f32x4 v = *(const f32x4*)&part2[128 + (4 * wave + l) * 4];
        outp[99] = v[0] + v[1] + v[2] + v[3] + bdv;
    }
}

extern "C" void kernel_launch(void* const* d_in, const int* in_sizes, int n_in,
                              void* d_out, int out_size, void* d_ws, size_t ws_size,
                              hipStream_t stream) {
    (void)in_sizes; (void)n_in; (void)out_size; (void)d_ws; (void)ws_size;
    const float* x   = (const float*)d_in[0];
    const float* Wih = (const float*)d_in[1];
    const float* Whh = (const float*)d_in[2];
    const float* bih = (const float*)d_in[3];
    const float* bhh = (const float*)d_in[4];
    const float* Wd  = (const float*)d_in[5];
    const float* bd  = (const float*)d_in[6];
    lstm_kernel<<<dim3(256), dim3(512), 0, stream>>>(
        x, Wih, Whh, bih, bhh, Wd, bd, (float*)d_out);
}